// Round 9
// baseline (361.827 us; speedup 1.0000x reference)
//
#include <hip/hip_runtime.h>
#include <hip/hip_bf16.h>
#include <hip/hip_fp16.h>
#include <math.h>

#define D_IN   128
#define D_RNI  32
#define HID    256

typedef _Float16 half8 __attribute__((ext_vector_type(8)));
typedef float    f32x4 __attribute__((ext_vector_type(4)));

// ---------------------------------------------------------------------------
// k_prep: fused {edge dtype detect} + {3x weight transpose/cast} + {counts=0}.
// ---------------------------------------------------------------------------
__global__ void k_prep(const unsigned int* __restrict__ ew, int nwords, int* __restrict__ mode,
                       const float* __restrict__ W1, __half* __restrict__ W1t,
                       const float* __restrict__ W2, __half* __restrict__ W2t,
                       const float* __restrict__ Wo, __half* __restrict__ Wot,
                       int* __restrict__ counts, int n) {
    int b = blockIdx.x;
    if (b == 0) {
        __shared__ unsigned int red[256];
        unsigned int acc = 0;
        for (int i = threadIdx.x; i < 1024; i += 256) {
            int idx = 2 * i + 1;
            if (idx < nwords) acc |= ew[idx];
        }
        red[threadIdx.x] = acc;
        __syncthreads();
        for (int s = 128; s > 0; s >>= 1) {
            if (threadIdx.x < s) red[threadIdx.x] |= red[threadIdx.x + s];
            __syncthreads();
        }
        if (threadIdx.x == 0) *mode = (red[0] == 0u) ? 1 : 0;
        return;
    }
    const int T1 = (D_IN + D_RNI) * HID;   // 40960  (160 blocks)
    const int T2 = HID * HID;              // 65536  (256 blocks each)
    const int TW = T1 + 2 * T2;            // 172032 (672 blocks)
    int i = (b - 1) * 256 + threadIdx.x;
    if (i < T1) {
        int k = i / HID, nn = i - k * HID;
        W1t[(size_t)nn * (D_IN + D_RNI) + k] = __float2half(W1[i]);
    } else if (i < T1 + T2) {
        int j = i - T1;
        int k = j / HID, nn = j - k * HID;
        W2t[(size_t)nn * HID + k] = __float2half(W2[j]);
    } else if (i < TW) {
        int j = i - T1 - T2;
        int k = j / HID, nn = j - k * HID;
        Wot[(size_t)nn * HID + k] = __float2half(Wo[j]);
    } else {
        int j = i - TW;
        if (j < n) counts[j] = 0;
    }
}

__global__ void k_count(const unsigned int* __restrict__ ew, const int* __restrict__ mode_p,
                        int* __restrict__ counts, int e) {
    int mode = *mode_p;
    int i = blockIdx.x * 256 + threadIdx.x;
    if (i >= e) return;
    int d = mode ? (int)ew[2 * ((size_t)e + i)] : (int)ew[(size_t)e + i];
    atomicAdd(&counts[d], 1);
}

// ---------------------------------------------------------------------------
// Scan: k_scan1 per-1024-chunk inclusive scans + chunk sums; k_scan3 folds the
// (<=64-entry) chunk-sum prefix via a wave reduce.
// ---------------------------------------------------------------------------
__global__ __launch_bounds__(1024) void k_scan1(const int* __restrict__ counts,
                                                int* __restrict__ incl,
                                                int* __restrict__ bsum, int n) {
    __shared__ int sd[1024];
    int t = threadIdx.x;
    int i = blockIdx.x * 1024 + t;
    int v = (i < n) ? counts[i] : 0;
    sd[t] = v;
    __syncthreads();
    for (int off = 1; off < 1024; off <<= 1) {
        int tmp = (t >= off) ? sd[t - off] : 0;
        __syncthreads();
        sd[t] += tmp;
        __syncthreads();
    }
    if (i < n) incl[i] = sd[t];
    if (t == 1023) bsum[blockIdx.x] = sd[1023];
}

__global__ void k_scan3(const int* __restrict__ counts, const int* __restrict__ incl,
                        const int* __restrict__ bsum,
                        int* __restrict__ rowptr, int* __restrict__ cursor,
                        float* __restrict__ dis, int n, int nb) {
    __shared__ int pre_s, tot_s;
    int t = threadIdx.x;
    int c = (blockIdx.x * 256) >> 10;
    if (t < 64) {
        int v   = (t < nb) ? bsum[t] : 0;
        int pre = (t < c)  ? v : 0;
        int tot = v;
        #pragma unroll
        for (int m = 32; m > 0; m >>= 1) {
            pre += __shfl_down(pre, m);
            tot += __shfl_down(tot, m);
        }
        if (t == 0) { pre_s = pre; tot_s = tot; }
    }
    __syncthreads();
    int i = blockIdx.x * 256 + t;
    if (i >= n) return;
    int excl = incl[i] - counts[i] + pre_s;
    rowptr[i] = excl;
    cursor[i] = excl;
    dis[i] = 1.0f / sqrtf((float)(counts[i] + 1));
    if (i == 0) rowptr[n] = tot_s;
}

// ---------------------------------------------------------------------------
// GEMM body (device fn): C[M x 256] = A[M x K] @ Bt^T  (Bt:[N=256][K] fp16).
// 512 threads = 8 waves as 2(M)x4(N); tile 128 M x 256 N. LSTR=40 padding,
// verified fragment layout.
// DBUF=true : LDS double-buffer (61440 B), one barrier per K-step — used by
//             standalone k_mgemm / k_scatgemm (2 blocks/CU is fine there).
// DBUF=false: single LDS buffer (30720 B), 2 barriers per K-step — used inside
//             k_aggemm so co-resident agg blocks keep ~4 blocks/CU occupancy.
// ---------------------------------------------------------------------------
#define KT 32
#define LSTR 40
template <bool A_F32, bool ADD_BIAS, bool HALF_OUT, bool DBUF>
__device__ __forceinline__ void gemm_body(int blk,
                                          const void* __restrict__ Av, int strideA, int KA,
                                          const void* __restrict__ A2v, int strideA2,
                                          const __half* __restrict__ Bt,
                                          const float* __restrict__ bias,
                                          void* Cv, int M, int K) {
    constexpr int NB = DBUF ? 2 : 1;
    __shared__ __half As[NB * 128 * LSTR];
    __shared__ __half Bs[NB * 256 * LSTR];
    int tid = threadIdx.x;
    int wave = tid >> 6, lane = tid & 63;
    int wm = wave >> 2, wn = wave & 3;          // 2 x 4 wave grid
    int q = lane >> 4, m16 = lane & 15;
    int r0 = blk * 128;

    int ar  = tid >> 2, akq = (tid & 3) * 8;    // A: 128 rows x 32 k
    int br  = tid >> 1, bkq = (tid & 1) * 16;   // B: 256 rows x 32 k

    int arow = r0 + ar; if (arow >= M) arow = M - 1;

    f32x4 acc[4][4] = {};

    float4 afr0, afr1;
    uint4  areg;
    uint4  breg0, breg1;

    auto loadA = [&](int k0) {
        if (A_F32) {
            const float* src; int stride, kk0;
            if (k0 < KA) { src = (const float*)Av;  stride = strideA;  kk0 = k0; }
            else         { src = (const float*)A2v; stride = strideA2; kk0 = k0 - KA; }
            const float* p = &src[(size_t)arow * stride + kk0 + akq];
            afr0 = *reinterpret_cast<const float4*>(p);
            afr1 = *reinterpret_cast<const float4*>(p + 4);
        } else {
            const __half* src = (const __half*)Av;
            areg = *reinterpret_cast<const uint4*>(&src[(size_t)arow * strideA + k0 + akq]);
        }
    };
    auto loadB = [&](int k0) {
        const __half* p = &Bt[(size_t)br * K + k0 + bkq];
        breg0 = *reinterpret_cast<const uint4*>(p);
        breg1 = *reinterpret_cast<const uint4*>(p + 8);
    };
    auto writeLDS = [&](int buf) {
        if (A_F32) {
            union { __half2 h2[4]; uint4 u; } uu;
            uu.h2[0] = __floats2half2_rn(afr0.x, afr0.y);
            uu.h2[1] = __floats2half2_rn(afr0.z, afr0.w);
            uu.h2[2] = __floats2half2_rn(afr1.x, afr1.y);
            uu.h2[3] = __floats2half2_rn(afr1.z, afr1.w);
            *reinterpret_cast<uint4*>(&As[buf * (128 * LSTR) + ar * LSTR + akq]) = uu.u;
        } else {
            *reinterpret_cast<uint4*>(&As[buf * (128 * LSTR) + ar * LSTR + akq]) = areg;
        }
        *reinterpret_cast<uint4*>(&Bs[buf * (256 * LSTR) + br * LSTR + bkq])     = breg0;
        *reinterpret_cast<uint4*>(&Bs[buf * (256 * LSTR) + br * LSTR + bkq + 8]) = breg1;
    };
    auto compute = [&](int buf) {
        half8 af[4], bf[4];
        #pragma unroll
        for (int mi = 0; mi < 4; ++mi)
            af[mi] = *reinterpret_cast<const half8*>(
                &As[buf * (128 * LSTR) + (wm * 64 + mi * 16 + m16) * LSTR + q * 8]);
        #pragma unroll
        for (int ni = 0; ni < 4; ++ni)
            bf[ni] = *reinterpret_cast<const half8*>(
                &Bs[buf * (256 * LSTR) + (wn * 64 + ni * 16 + m16) * LSTR + q * 8]);
        #pragma unroll
        for (int mi = 0; mi < 4; ++mi)
            #pragma unroll
            for (int ni = 0; ni < 4; ++ni)
                acc[mi][ni] = __builtin_amdgcn_mfma_f32_16x16x32_f16(af[mi], bf[ni], acc[mi][ni], 0, 0, 0);
    };

    const int S = K / KT;
    if (DBUF) {
        loadA(0); loadB(0);
        writeLDS(0);
        __syncthreads();
        for (int t = 0; t < S; ++t) {
            int cur = t & 1;
            if (t + 1 < S) { loadA((t + 1) * KT); loadB((t + 1) * KT); }
            compute(cur);
            if (t + 1 < S) writeLDS(cur ^ 1);
            __syncthreads();
        }
    } else {
        loadA(0); loadB(0);
        for (int t = 0; t < S; ++t) {
            __syncthreads();
            writeLDS(0);
            __syncthreads();
            if (t + 1 < S) { loadA((t + 1) * KT); loadB((t + 1) * KT); }
            compute(0);
        }
    }

    #pragma unroll
    for (int mi = 0; mi < 4; ++mi) {
        #pragma unroll
        for (int r = 0; r < 4; ++r) {
            int row = r0 + wm * 64 + mi * 16 + q * 4 + r;
            if (row >= M) continue;
            #pragma unroll
            for (int ni = 0; ni < 4; ++ni) {
                int col = wn * 64 + ni * 16 + m16;
                float v = acc[mi][ni][r];
                if (ADD_BIAS) v += bias[col];
                if (HALF_OUT) ((__half*)Cv)[(size_t)row * HID + col] = __float2half(v);
                else          ((float*)Cv)[(size_t)row * HID + col] = v;
            }
        }
    }
}

template <bool A_F32, bool ADD_BIAS, bool HALF_OUT>
__global__ __launch_bounds__(512, 4) void k_mgemm(const void* __restrict__ Av, int strideA, int KA,
                                                  const void* __restrict__ A2v, int strideA2,
                                                  const __half* __restrict__ Bt,
                                                  const float* __restrict__ bias,
                                                  void* Cv, int M, int K) {
    gemm_body<A_F32, ADD_BIAS, HALF_OUT, true>(blockIdx.x, Av, strideA, KA, A2v, strideA2,
                                               Bt, bias, Cv, M, K);
}

// ---------------------------------------------------------------------------
// Aggregation body, wave-per-node (round-0 verified inner loop — do not touch):
// h[i,c] = relu( sum_e xh[src_e,c]*dis[src]*dis[i] + xh[i,c]*dis[i]^2 + b[c] )
// ~59 us full-range = 218 MB of L2-miss traffic at ~3.7-4 TB/s, the effective
// ceiling for this random-line gather (rounds 1-2: NT hints / deeper unrolls
// only ADD bytes).
// ---------------------------------------------------------------------------
__device__ __forceinline__ void agg_node(int i,
                                         const __half* __restrict__ xh,
                                         const int* __restrict__ rowptr,
                                         const int* __restrict__ csr,
                                         const float* __restrict__ dis,
                                         const float* __restrict__ bias,
                                         __half* __restrict__ outh) {
    int lane = threadIdx.x & 63;
    int c4 = lane * 4;
    float disd = dis[i];
    int e0 = rowptr[i], e1 = rowptr[i + 1];

    float acc0, acc1, acc2, acc3;
    {
        uint2 v = *reinterpret_cast<const uint2*>(&xh[(size_t)i * HID + c4]);
        float2 f0 = __half22float2(*reinterpret_cast<__half2*>(&v.x));
        float2 f1 = __half22float2(*reinterpret_cast<__half2*>(&v.y));
        float ws = disd * disd;
        acc0 = f0.x * ws; acc1 = f0.y * ws; acc2 = f1.x * ws; acc3 = f1.y * ws;
    }

    for (int e = e0; e < e1; e += 64) {
        int cnt = min(64, e1 - e);
        int sreg = 0; float wreg = 0.0f;
        if (lane < cnt) {
            sreg = csr[e + lane];
            wreg = dis[sreg] * disd;
        }
        int j = 0;
        for (; j + 4 <= cnt; j += 4) {
            int   s0 = __shfl(sreg, j + 0), s1 = __shfl(sreg, j + 1);
            int   s2 = __shfl(sreg, j + 2), s3 = __shfl(sreg, j + 3);
            float w0 = __shfl(wreg, j + 0), w1 = __shfl(wreg, j + 1);
            float w2 = __shfl(wreg, j + 2), w3 = __shfl(wreg, j + 3);
            uint2 v0 = *reinterpret_cast<const uint2*>(&xh[(size_t)s0 * HID + c4]);
            uint2 v1 = *reinterpret_cast<const uint2*>(&xh[(size_t)s1 * HID + c4]);
            uint2 v2 = *reinterpret_cast<const uint2*>(&xh[(size_t)s2 * HID + c4]);
            uint2 v3 = *reinterpret_cast<const uint2*>(&xh[(size_t)s3 * HID + c4]);
            float2 a0 = __half22float2(*reinterpret_cast<__half2*>(&v0.x));
            float2 b0 = __half22float2(*reinterpret_cast<__half2*>(&v0.y));
            float2 a1 = __half22float2(*reinterpret_cast<__half2*>(&v1.x));
            float2 b1 = __half22float2(*reinterpret_cast<__half2*>(&v1.y));
            float2 a2 = __half22float2(*reinterpret_cast<__half2*>(&v2.x));
            float2 b2 = __half22float2(*reinterpret_cast<__half2*>(&v2.y));
            float2 a3 = __half22float2(*reinterpret_cast<__half2*>(&v3.x));
            float2 b3 = __half22float2(*reinterpret_cast<__half2*>(&v3.y));
            acc0 = fmaf(a0.x, w0, acc0); acc1 = fmaf(a0.y, w0, acc1);
            acc2 = fmaf(b0.x, w0, acc2); acc3 = fmaf(b0.y, w0, acc3);
            acc0 = fmaf(a1.x, w1, acc0); acc1 = fmaf(a1.y, w1, acc1);
            acc2 = fmaf(b1.x, w1, acc2); acc3 = fmaf(b1.y, w1, acc3);
            acc0 = fmaf(a2.x, w2, acc0); acc1 = fmaf(a2.y, w2, acc1);
            acc2 = fmaf(b2.x, w2, acc2); acc3 = fmaf(b2.y, w2, acc3);
            acc0 = fmaf(a3.x, w3, acc0); acc1 = fmaf(a3.y, w3, acc1);
            acc2 = fmaf(b3.x, w3, acc2); acc3 = fmaf(b3.y, w3, acc3);
        }
        for (; j < cnt; ++j) {
            int   s = __shfl(sreg, j);
            float w = __shfl(wreg, j);
            uint2 v = *reinterpret_cast<const uint2*>(&xh[(size_t)s * HID + c4]);
            float2 a = __half22float2(*reinterpret_cast<__half2*>(&v.x));
            float2 b = __half22float2(*reinterpret_cast<__half2*>(&v.y));
            acc0 = fmaf(a.x, w, acc0); acc1 = fmaf(a.y, w, acc1);
            acc2 = fmaf(b.x, w, acc2); acc3 = fmaf(b.y, w, acc3);
        }
    }

    float4 bb = *reinterpret_cast<const float4*>(&bias[c4]);
    union { __half2 h2[2]; uint2 u; } o;
    o.h2[0] = __floats2half2_rn(fmaxf(acc0 + bb.x, 0.0f), fmaxf(acc1 + bb.y, 0.0f));
    o.h2[1] = __floats2half2_rn(fmaxf(acc2 + bb.z, 0.0f), fmaxf(acc3 + bb.w, 0.0f));
    *reinterpret_cast<uint2*>(&outh[(size_t)i * HID + c4]) = o.u;
}

__global__ __launch_bounds__(256) void k_agg(const __half* __restrict__ xh,
                                             const int* __restrict__ rowptr,
                                             const int* __restrict__ csr,
                                             const float* __restrict__ dis,
                                             const float* __restrict__ bias,
                                             __half* __restrict__ outh, int i0, int i1) {
    int i = i0 + blockIdx.x * 4 + (threadIdx.x >> 6);
    if (i < i1) agg_node(i, xh, rowptr, csr, dis, bias, outh);
}

// ---------------------------------------------------------------------------
// Fused agg(H1) + gemm(H0) — layer-seam pipeline (round-9).
// Legal split: gemm tile rows only need agg output for THOSE rows (row-local),
// while agg's gather needs ALL gemm-output rows. So per seam:
//   agg(H0) -> { agg(H1) || gemm(H0) } -> gemm(H1).
// agg (fetch-bound gather, 0 MFMA, 28% VALU) and gemm (MFMA/LDS) use disjoint
// pipes. gemm blocks FIRST in grid (196 << capacity; round-7 lesson), agg
// blocks backfill from t=0. gemm uses the single-LDS-buffer body (30720 B) so
// agg blocks keep ~4 blocks/CU instead of being LDS-throttled to 2.
// Buffers are raced-checked: agg writes rows [half,n) of its out buffer; gemm
// reads rows [0,half) of the same or different buffer — always disjoint.
// ---------------------------------------------------------------------------
template <bool ADD_BIAS_G, bool HALF_OUT_G>
__global__ __launch_bounds__(512, 4) void k_aggemm(
        const __half* __restrict__ Ag, const __half* __restrict__ Btg,
        const float* __restrict__ biasg, void* Cg, int Mg, int G,
        const __half* __restrict__ xa, const int* __restrict__ rowptr,
        const int* __restrict__ csr, const float* __restrict__ dis,
        const float* __restrict__ biasa, __half* __restrict__ outa, int i0, int i1) {
    if ((int)blockIdx.x < G) {
        gemm_body<false, ADD_BIAS_G, HALF_OUT_G, false>(blockIdx.x, Ag, HID, HID, nullptr, 0,
                                                        Btg, biasg, Cg, Mg, HID);
        return;
    }
    int i = i0 + ((int)blockIdx.x - G) * 8 + ((int)threadIdx.x >> 6);
    if (i < i1) agg_node(i, xa, rowptr, csr, dis, biasa, outa);
}

// ---------------------------------------------------------------------------
// Fused persistent scatter + layer-1 GEMM (round-8, verified 60.4 us).
// Scatter = 121 persistent grid-strided blocks at blockIdx 0..120, GEMM at
// 121..511; 121+391 = 512 = exact resident capacity -> co-resident from t=0.
// ---------------------------------------------------------------------------
#define SCAT_BLKS 121
__global__ __launch_bounds__(512, 4) void k_scatgemm(
        const unsigned int* __restrict__ ew, const int* __restrict__ mode_p,
        int* __restrict__ cursor, int* __restrict__ csr, int e,
        const float* __restrict__ x, const float* __restrict__ rni,
        const __half* __restrict__ W1t, __half* __restrict__ xh, int M, int K) {
    if ((int)blockIdx.x >= SCAT_BLKS) {
        gemm_body<true, false, true, true>((int)blockIdx.x - SCAT_BLKS, x, D_IN, D_IN, rni, D_RNI,
                                           W1t, nullptr, xh, M, K);
        return;
    }
    const int t0     = (int)blockIdx.x * 512 + (int)threadIdx.x;
    const int stride = SCAT_BLKS * 512 * 4;
    const int mode   = *mode_p;
    for (int i = t0 * 4; i < e; i += stride) {
        if (i + 4 <= e) {
            int s0, s1, s2, s3, d0, d1, d2, d3;
            if (mode) {
                s0 = (int)ew[2 * (size_t)(i + 0)]; d0 = (int)ew[2 * ((size_t)e + i + 0)];
                s1 = (int)ew[2 * (size_t)(i + 1)]; d1 = (int)ew[2 * ((size_t)e + i + 1)];
                s2 = (int)ew[2 * (size_t)(i + 2)]; d2 = (int)ew[2 * ((size_t)e + i + 2)];
                s3 = (int)ew[2 * (size_t)(i + 3)]; d3 = (int)ew[2 * ((size_t)e + i + 3)];
            } else {
                s0 = (int)ew[(size_t)(i + 0)]; d0 = (int)ew[(size_t)e + i + 0];
                s1 = (int)ew[(size_t)(i + 1)]; d1 = (int)ew[(size_t)e + i + 1];
                s2 = (int)ew[(size_t)(i + 2)]; d2 = (int)ew[(size_t)e + i + 2];
                s3 = (int)ew[(size_t)(i + 3)]; d3 = (int)ew[(size_t)e + i + 3];
            }
            int p0 = atomicAdd(&cursor[d0], 1);
            int p1 = atomicAdd(&cursor[d1], 1);
            int p2 = atomicAdd(&cursor[d2], 1);
            int p3 = atomicAdd(&cursor[d3], 1);
            csr[p0] = s0; csr[p1] = s1; csr[p2] = s2; csr[p3] = s3;
        } else {
            for (int j = i; j < e; ++j) {
                int s, d;
                if (mode) { s = (int)ew[2 * (size_t)j]; d = (int)ew[2 * ((size_t)e + j)]; }
                else      { s = (int)ew[(size_t)j];     d = (int)ew[(size_t)e + j]; }
                int pos = atomicAdd(&cursor[d], 1);
                csr[pos] = s;
            }
        }
    }
}

// ---------------------------------------------------------------------------
extern "C" void kernel_launch(void* const* d_in, const int* in_sizes, int n_in,
                              void* d_out, int out_size, void* d_ws, size_t ws_size,
                              hipStream_t stream) {
    const float* x     = (const float*)d_in[0];
    const float* rni   = (const float*)d_in[1];
    const unsigned int* ew = (const unsigned int*)d_in[2];
    const float* W1    = (const float*)d_in[3];
    const float* b1    = (const float*)d_in[4];
    const float* W2    = (const float*)d_in[5];
    const float* b2    = (const float*)d_in[6];
    const float* W_out = (const float*)d_in[7];
    const float* b_out = (const float*)d_in[8];
    float* out = (float*)d_out;

    const int n  = in_sizes[0] / D_IN;     // 50000
    const int e  = in_sizes[2] / 2;        // 800000
    const int nb = (n + 1023) / 1024;
    const int K1 = D_IN + D_RNI;           // 160

    char* ws = (char*)d_ws;
    size_t off = 0;
    auto carve = [&](size_t bytes) {
        char* p = ws + off;
        off = (off + bytes + 255) & ~(size_t)255;
        return p;
    };
    __half* xh    = (__half*)carve((size_t)n * HID * sizeof(__half));   // A: 25.6 MB
    __half* h     = (__half*)carve((size_t)n * HID * sizeof(__half));   // B: 25.6 MB
    __half* xh2   = (__half*)carve((size_t)n * HID * sizeof(__half));   // C: 25.6 MB
    __half* W1t   = (__half*)carve((size_t)K1 * HID * sizeof(__half));
    __half* W2t   = (__half*)carve((size_t)HID * HID * sizeof(__half));
    __half* Wot   = (__half*)carve((size_t)HID * HID * sizeof(__half));
    int*   counts = (int*)carve((size_t)n * sizeof(int));
    int*   incl   = (int*)carve((size_t)n * sizeof(int));
    int*   bsum   = (int*)carve((size_t)(nb + 1) * sizeof(int));
    int*   rowptr = (int*)carve((size_t)(n + 1) * sizeof(int));
    int*   cursor = (int*)carve((size_t)n * sizeof(int));
    float* dis    = (float*)carve((size_t)n * sizeof(float));
    int*   csr    = (int*)carve((size_t)e * sizeof(int));
    int*   mode   = (int*)carve(sizeof(int));
    (void)ws_size;

    const int eb = (e + 255) / 256;
    const int gemm_blocks = (n + 127) / 128;     // 391
    const int TW = K1 * HID + 2 * HID * HID;
    const int prep_blocks = 1 + (TW + n + 255) / 256;

    // half-split for the seam pipeline: multiple of 128 (gemm tile) and 8.
    int half = ((n / 2 + 127) / 128) * 128;      // 25088
    if (half > n) half = (n / 128) * 128;
    const int G2      = half / 128;              // gemm blocks for H0 (196)
    const int aggH0b  = (half + 3) / 4;          // standalone agg H0 blocks
    const int aggH1b  = (n - half + 7) / 8;      // fused agg H1 blocks (8 nodes/blk)
    const int gH1b    = (n - half + 127) / 128;  // standalone gemm H1 blocks

    // --- prep (detect + weight cvt + counts=0) and CSR chain
    k_prep<<<prep_blocks, 256, 0, stream>>>(ew, 2 * e, mode, W1, W1t, W2, W2t, W_out, Wot,
                                            counts, n);
    k_count<<<eb, 256, 0, stream>>>(ew, mode, counts, e);
    k_scan1<<<nb, 1024, 0, stream>>>(counts, incl, bsum, n);
    k_scan3<<<(n + 255) / 256, 256, 0, stream>>>(counts, incl, bsum, rowptr, cursor, dis, n, nb);

    // --- fused: persistent scatter + layer-1 GEMM (x,rni -> A=xh)
    k_scatgemm<<<SCAT_BLKS + gemm_blocks, 512, 0, stream>>>(ew, mode, cursor, csr, e,
                                                            x, rni, W1t, xh, n, K1);

    // --- seam 1: agg1 (A->B, bias b1) pipelined with gemm2 (B->C)
    k_agg<<<aggH0b, 256, 0, stream>>>(xh, rowptr, csr, dis, b1, h, 0, half);
    k_aggemm<false, true><<<G2 + aggH1b, 512, 0, stream>>>(
        h, W2t, nullptr, xh2, half, G2,
        xh, rowptr, csr, dis, b1, h, half, n);
    k_mgemm<false, false, true><<<gH1b, 512, 0, stream>>>(
        h + (size_t)half * HID, HID, HID, nullptr, 0, W2t, nullptr,
        xh2 + (size_t)half * HID, n - half, HID);

    // --- seam 2: agg2 (C->A, bias b2) pipelined with gemm3 (A->out fp32+bias)
    k_agg<<<aggH0b, 256, 0, stream>>>(xh2, rowptr, csr, dis, b2, xh, 0, half);
    k_aggemm<true, false><<<G2 + aggH1b, 512, 0, stream>>>(
        xh, Wot, b_out, out, half, G2,
        xh2, rowptr, csr, dis, b2, xh, half, n);
    k_mgemm<false, true, false><<<gH1b, 512, 0, stream>>>(
        xh + (size_t)half * HID, HID, HID, nullptr, 0, Wot, b_out,
        out + (size_t)half * HID, n - half, HID);
}